// Round 18
// baseline (18515.294 us; speedup 1.0000x reference)
//
#include <hip/hip_runtime.h>
#include <math.h>

#define T_STEPS 4096
#define HID     1024
#define G4      4096   // 4*HID gate rows
#define NB      128    // recurrence blocks
#define TPB     256    // 4 waves per block

// ---- agent-scope atomic helpers ----
__device__ __forceinline__ unsigned long long ld64(const unsigned long long* p) {
    return __hip_atomic_load(p, __ATOMIC_RELAXED, __HIP_MEMORY_SCOPE_AGENT);
}
__device__ __forceinline__ void st_flag(unsigned* p, unsigned v) {
    __hip_atomic_store(p, v, __ATOMIC_RELAXED, __HIP_MEMORY_SCOPE_AGENT);
}
__device__ __forceinline__ void st_h(float* p, float v) {
    __hip_atomic_store(p, v, __ATOMIC_RELAXED, __HIP_MEMORY_SCOPE_AGENT);
}
__device__ __forceinline__ float fsigmoid(float x) {
    return __fdividef(1.0f, 1.0f + __expf(-x));
}
__device__ __forceinline__ float ftanh(float x) {
    return __fdividef(2.0f, 1.0f + __expf(-2.0f * x)) - 1.0f;
}

// ---------------------------------------------------------------------------
// Kernel 1: xg[t][r] = dot(x[t,:], w_ih[r,:]) + b_ih[r] + b_hh[r]
// f32 GEMM, 64x64 tile, K-chunk 32, 256 threads, 4x4 per thread.
// Block (0,0) threads<64 zero the 128 u32 flags (graph-replay reset).
// ---------------------------------------------------------------------------
__global__ __launch_bounds__(256) void xg_gemm(
    const float* __restrict__ x, const float* __restrict__ w_ih,
    const float* __restrict__ b_ih, const float* __restrict__ b_hh,
    float* __restrict__ xg, unsigned long long* __restrict__ flags64)
{
    if (blockIdx.x == 0 && blockIdx.y == 0 && threadIdx.x < 64)
        flags64[threadIdx.x] = 0ull;

    __shared__ float Xs[32][68];   // [k][m], pad kills conflicts
    __shared__ float Ws[32][68];   // [k][n]

    const int t0  = blockIdx.y * 64;
    const int n0  = blockIdx.x * 64;
    const int thr = threadIdx.x;
    const int tx  = thr & 15;      // n-group
    const int ty  = thr >> 4;      // m-group

    float acc[4][4] = {};

    for (int kk = 0; kk < 1024; kk += 32) {
        #pragma unroll
        for (int i = 0; i < 2; i++) {
            int flat = thr + i * 256;       // 0..511
            int m    = flat >> 3;           // 0..63
            int kc   = flat & 7;            // k-chunk (4 floats)
            float4 xv = *(const float4*)(x    + (size_t)(t0 + m) * 1024 + kk + kc * 4);
            float4 wv = *(const float4*)(w_ih + (size_t)(n0 + m) * 1024 + kk + kc * 4);
            Xs[kc*4+0][m] = xv.x; Xs[kc*4+1][m] = xv.y;
            Xs[kc*4+2][m] = xv.z; Xs[kc*4+3][m] = xv.w;
            Ws[kc*4+0][m] = wv.x; Ws[kc*4+1][m] = wv.y;
            Ws[kc*4+2][m] = wv.z; Ws[kc*4+3][m] = wv.w;
        }
        __syncthreads();
        #pragma unroll
        for (int k = 0; k < 32; k++) {
            float4 a4 = *(const float4*)&Xs[k][ty * 4];
            float4 b4 = *(const float4*)&Ws[k][tx * 4];
            float av[4] = {a4.x, a4.y, a4.z, a4.w};
            float bv[4] = {b4.x, b4.y, b4.z, b4.w};
            #pragma unroll
            for (int i = 0; i < 4; i++)
                #pragma unroll
                for (int j = 0; j < 4; j++)
                    acc[i][j] = fmaf(av[i], bv[j], acc[i][j]);
        }
        __syncthreads();
    }

    float4 bi = *(const float4*)(b_ih + n0 + tx * 4);
    float4 bh = *(const float4*)(b_hh + n0 + tx * 4);
    float bb[4] = {bi.x + bh.x, bi.y + bh.y, bi.z + bh.z, bi.w + bh.w};
    #pragma unroll
    for (int i = 0; i < 4; i++) {
        float4 o;
        o.x = acc[i][0] + bb[0]; o.y = acc[i][1] + bb[1];
        o.z = acc[i][2] + bb[2]; o.w = acc[i][3] + bb[3];
        *(float4*)(xg + (size_t)(t0 + ty * 4 + i) * G4 + n0 + tx * 4) = o;
    }
}

// ---------------------------------------------------------------------------
// Kernel 2: persistent recurrence. 128 blocks x 256 threads,
// __launch_bounds__(256,1) -> full 512-VGPR cap so the 128 weight
// floats/thread can stay resident (r7 proved 64 floats stick under this
// cap; this is the 128-float test).
// Block b owns units [8b, 8b+8). Wave rg (0..3) owns units 8b+2rg, +1
// x 4 gates = 8 rows (r2's exact per-thread dot shape: 8x16).
// Handoff (low-congestion flag protocol, MONOTONE >= — the r15 equality
// spin deadlocked: a late block can miss the transient all==t+1 window
// on a single incrementing flag; >= is hang-free and the buffer-p
// overwrite race stays closed because an overwriter needs THIS block's
// flag >= t+2 first):
//   producers: untagged f32 agent stores -> __syncthreads (drains vmcnt)
//   -> thread 0 sets flag32[b]=t+2.
//   consumers: ONLY wave 0 spins; lane ec polls flags64[ec] (2 blocks/lane,
//   64 requests/round, 8K spinner-lanes chip-wide) -> barrier -> one-shot
//   h loads -> stage -> barrier -> compute -> publish -> barrier -> flag.
// ---------------------------------------------------------------------------
__global__ __launch_bounds__(256, 1) void lstm_rec(
    const float* __restrict__ xg, const float* __restrict__ w_hh,
    const float* __restrict__ h0, const float* __restrict__ c0,
    const float* __restrict__ w_out, const float* __restrict__ b_out,
    float* __restrict__ h_pub,                 // [2][HID] f32
    unsigned long long* __restrict__ flags64,  // 64 u64 = 128 u32 flags
    float* __restrict__ out)
{
    __shared__ float h_lds[2][64 * 20];   // double-buffered, stride-20 chunks
    __shared__ float red_lds[4];

    const int thr = threadIdx.x;       // 0..255
    const int b   = blockIdx.x;        // 0..127
    const int rg  = thr >> 6;          // wave 0..3
    const int ec  = thr & 63;          // lane 0..63

    unsigned* flags32 = (unsigned*)flags64;

    // this wave's 8 rows: gate = rr&3, unit = 8b + 2rg + (rr>>2)
    int grow[8];
    #pragma unroll
    for (int rr = 0; rr < 8; rr++)
        grow[rr] = (rr & 3) * HID + 8 * b + 2 * rg + (rr >> 2);

    // ---- preload weights: w[rr][q] = w_hh[grow[rr]][16ec + 4q .. +3]
    float4 w[8][4];
    #pragma unroll
    for (int rr = 0; rr < 8; rr++) {
        const float* wr = w_hh + (size_t)grow[rr] * HID + ec * 16;
        #pragma unroll
        for (int q = 0; q < 4; q++)
            w[rr][q] = *(const float4*)(wr + q * 4);
    }

    // ---- init: c on lanes 0/4 of each wave; publish h0 slice; flag=1
    const int myunit = 8 * b + 2 * rg + (ec >> 2);    // valid on lanes 0,4
    float c = 0.0f;
    if (ec == 0 || ec == 4) {
        c = c0[myunit];
        st_h(&h_pub[0 * HID + myunit], h0[myunit]);
    }
    __syncthreads();                   // drain init stores (vmcnt 0)
    if (thr == 0) st_flag(&flags32[b], 1u);

    const int u0 = 4 * thr;            // this thread's four staged h units
    const int l0 = (u0 >> 4) * 20 + (u0 & 15);
    const int xrow = grow[ec & 7];     // xg row whose total this lane holds

    for (int t = 0; t < T_STEPS; t++) {
        const int p = t & 1;

        // xg prefetch (independent of the handoff)
        float xgv = xg[(size_t)t * G4 + xrow];

        // ---- wave 0 spins: lane ec covers blocks 2ec, 2ec+1 (MONOTONE >=)
        if (rg == 0) {
            const unsigned tag = (unsigned)(t + 1);
            const unsigned long long* fp = &flags64[ec];
            unsigned long long v = ld64(fp);
            while (!__all(((unsigned)v >= tag) &
                          ((unsigned)(v >> 32) >= tag)))
                v = ld64(fp);
        }
        __syncthreads();

        // ---- one-shot h fetch: 4 floats (2 ld64) per thread
        const unsigned long long* hp =
            (const unsigned long long*)&h_pub[p * HID + u0];
        unsigned long long v0 = ld64(hp), v1 = ld64(hp + 1);
        float4 hw;
        hw.x = __uint_as_float((unsigned)v0);
        hw.y = __uint_as_float((unsigned)(v0 >> 32));
        hw.z = __uint_as_float((unsigned)v1);
        hw.w = __uint_as_float((unsigned)(v1 >> 32));
        *(float4*)&h_lds[p][l0] = hw;
        __syncthreads();

        // ---- dot: 8 rows x 16 elems per thread
        float4 h4[4];
        #pragma unroll
        for (int q = 0; q < 4; q++)
            h4[q] = *(const float4*)&h_lds[p][ec * 20 + q * 4];

        float a[8];
        #pragma unroll
        for (int rr = 0; rr < 8; rr++) {
            float s0 = 0.f, s1 = 0.f, s2 = 0.f, s3 = 0.f;
            #pragma unroll
            for (int q = 0; q < 4; q++) {
                s0 = fmaf(w[rr][q].x, h4[q].x, s0);
                s1 = fmaf(w[rr][q].y, h4[q].y, s1);
                s2 = fmaf(w[rr][q].z, h4[q].z, s2);
                s3 = fmaf(w[rr][q].w, h4[q].w, s3);
            }
            a[rr] = (s0 + s1) + (s2 + s3);
        }

        // ---- multi-value fold: 8 accs x 64 lanes -> lane ec holds row ec&7
        const bool b0 = (ec & 1), b1 = (ec & 2), b2 = (ec & 4);
        float f[4];
        #pragma unroll
        for (int i = 0; i < 4; i++) {
            float send = b0 ? a[2*i] : a[2*i+1];
            float recv = __shfl_xor(send, 1, 64);
            f[i] = (b0 ? a[2*i+1] : a[2*i]) + recv;
        }
        float g2[2];
        #pragma unroll
        for (int i = 0; i < 2; i++) {
            float send = b1 ? f[2*i] : f[2*i+1];
            float recv = __shfl_xor(send, 2, 64);
            g2[i] = (b1 ? f[2*i+1] : f[2*i]) + recv;
        }
        float d;
        {
            float send = b2 ? g2[0] : g2[1];
            float recv = __shfl_xor(send, 4, 64);
            d = (b2 ? g2[1] : g2[0]) + recv;
        }
        d += __shfl_xor(d, 8, 64);
        d += __shfl_xor(d, 16, 64);
        d += __shfl_xor(d, 32, 64);
        d += xgv;                       // full preact for row grow[ec&7]

        // ---- gather {i,f,g,o} onto lanes 0 (unit 2rg) and 4 (unit 2rg+1)
        float v1g = __shfl_xor(d, 1, 64);
        float v2g = __shfl_xor(d, 2, 64);
        float v3g = __shfl_xor(d, 3, 64);

        if (ec == 0 || ec == 4) {
            float si = fsigmoid(d);
            float sf = fsigmoid(v1g);
            float tg = ftanh(v2g);
            float so = fsigmoid(v3g);
            c = sf * c + si * tg;
            float hn = so * ftanh(c);
            st_h(&h_pub[(p ^ 1) * HID + myunit], hn);
        }
        __syncthreads();                 // drain publish stores (vmcnt 0)
        if (thr == 0) st_flag(&flags32[b], (unsigned)(t + 2));
    }

    // ---- tail: block 0 computes pred = tanh(w_out . h_final + b_out)
    if (b == 0) {
        if (rg == 0) {
            const unsigned tag = (unsigned)(T_STEPS + 1);
            const unsigned long long* fp = &flags64[ec];
            unsigned long long v = ld64(fp);
            while (!__all(((unsigned)v >= tag) &
                          ((unsigned)(v >> 32) >= tag)))
                v = ld64(fp);
        }
        __syncthreads();
        const unsigned long long* hp =
            (const unsigned long long*)&h_pub[0 * HID + u0];   // h_4096, buf 0
        unsigned long long v0 = ld64(hp), v1 = ld64(hp + 1);
        float part = __uint_as_float((unsigned)v0)         * w_out[u0]
                   + __uint_as_float((unsigned)(v0 >> 32)) * w_out[u0 + 1]
                   + __uint_as_float((unsigned)v1)         * w_out[u0 + 2]
                   + __uint_as_float((unsigned)(v1 >> 32)) * w_out[u0 + 3];
        #pragma unroll
        for (int m = 1; m < 64; m <<= 1)
            part += __shfl_xor(part, m, 64);
        if (ec == 0) red_lds[rg] = part;
        __syncthreads();
        if (thr == 0) {
            float s = red_lds[0] + red_lds[1] + red_lds[2] + red_lds[3];
            out[0] = tanhf(s + b_out[0]);
        }
    }
}

// ---------------------------------------------------------------------------
extern "C" void kernel_launch(void* const* d_in, const int* in_sizes, int n_in,
                              void* d_out, int out_size, void* d_ws, size_t ws_size,
                              hipStream_t stream) {
    const float* x     = (const float*)d_in[0];
    const float* h0    = (const float*)d_in[1];
    const float* c0    = (const float*)d_in[2];
    const float* w_ih  = (const float*)d_in[3];
    const float* w_hh  = (const float*)d_in[4];
    const float* b_ih  = (const float*)d_in[5];
    const float* b_hh  = (const float*)d_in[6];
    const float* w_out = (const float*)d_in[7];
    const float* b_out = (const float*)d_in[8];
    float* out = (float*)d_out;

    char* ws = (char*)d_ws;
    float*              xg      = (float*)ws;                              // 64 MiB
    float*              h_pub   = (float*)(ws + (size_t)T_STEPS * G4 * 4); // 8 KiB
    unsigned long long* flags64 = (unsigned long long*)(ws + (size_t)T_STEPS * G4 * 4 + 12288);

    xg_gemm<<<dim3(64, 64), 256, 0, stream>>>(x, w_ih, b_ih, b_hh, xg, flags64);
    lstm_rec<<<NB, TPB, 0, stream>>>(xg, w_hh, h0, c0, w_out, b_out,
                                     h_pub, flags64, out);
}